// Round 11
// baseline (205.658 us; speedup 1.0000x reference)
//
#include <hip/hip_runtime.h>
#include <math.h>

// Problem constants: B=8, N=2048, D=512, S=4096
#define BATCH 8
#define NNODES 2048
#define DDIM 512
#define SWAPS 4096
#define M_TOTAL (BATCH * SWAPS)   // 32768
#define KD DDIM                   // 512 (dense GEMM K)
#define K2 DDIM                   // 512
#define N2 (DDIM / 2)             // 256

typedef __attribute__((ext_vector_type(8))) __bf16 bf16x8;   // MFMA A/B frag
typedef __attribute__((ext_vector_type(4))) float f32x4;      // MFMA C/D frag
typedef __attribute__((ext_vector_type(8))) unsigned short us8;
typedef unsigned short ushort_t;

// tanh-approx GELU (max |err| vs exact erf-GELU ~5e-4)
__device__ __forceinline__ float gelu_fast(float x) {
    const float u = 0.7978845608028654f * x * fmaf(0.044715f * x, x, 1.0f);
    const float e = __expf(-2.0f * fabsf(u));
    float t = (1.0f - e) / (1.0f + e);
    t = copysignf(t, u);
    return 0.5f * x * (1.0f + t);
}
__device__ __forceinline__ float softplus_f(float x) {
    return fmaxf(x, 0.0f) + log1pf(expf(-fabsf(x)));
}
__device__ __forceinline__ unsigned short f2bf(float f) {
    unsigned int u = __builtin_bit_cast(unsigned int, f);
    u += 0x7FFFu + ((u >> 16) & 1u);
    return (unsigned short)(u >> 16);
}
__device__ __forceinline__ float bf2f(unsigned short s) {
    return __builtin_bit_cast(float, (unsigned int)s << 16);
}
__device__ __forceinline__ void glds16(const void* g, void* l) {
    __builtin_amdgcn_global_load_lds(
        (const __attribute__((address_space(1))) void*)g,
        (__attribute__((address_space(3))) void*)l, 16, 0, 0);
}

// ---------------------------------------------------------------------------
// convert: h -> h_bf;  W1 -> W1pt[j][d] via LDS transpose (contiguous 16B
// global stores);  W2 -> W2f fragment-major [kc*8192 + n*32 + quad*8 + pos].
// ---------------------------------------------------------------------------
__global__ __launch_bounds__(256) void convert_kernel(
    const float* __restrict__ h, const float* __restrict__ W1,
    const float* __restrict__ W2, ushort_t* __restrict__ h_bf,
    ushort_t* __restrict__ W1pt, ushort_t* __restrict__ W2f)
{
    const int bid = blockIdx.x;
    const int tid = threadIdx.x;
    if (bid < 8192) {                       // h: 8M elems
        size_t i = ((size_t)bid * 256 + tid) * 4;
        float4 v = *(const float4*)(h + i);
        ushort4 o = { f2bf(v.x), f2bf(v.y), f2bf(v.z), f2bf(v.w) };
        *(ushort4*)(h_bf + i) = o;
    } else if (bid < 8192 + 256) {          // W1 transpose: 64k x 64n tiles
        __shared__ ushort_t sT[64][72];     // [n_local][k_local+pad]
        const int tb = bid - 8192;
        const int kt = tb >> 3, nt = tb & 7;     // 32 k-tiles, 8 n-tiles
        const int kl = tid >> 4;                 // 0..15 (per pass)
        const int n4 = (tid & 15) * 4;
        #pragma unroll
        for (int p = 0; p < 4; ++p) {
            const int k_local = p * 16 + kl;
            float4 v = *(const float4*)(W1 + (size_t)(kt * 64 + k_local) * 512
                                        + nt * 64 + n4);
            sT[n4 + 0][k_local] = f2bf(v.x);
            sT[n4 + 1][k_local] = f2bf(v.y);
            sT[n4 + 2][k_local] = f2bf(v.z);
            sT[n4 + 3][k_local] = f2bf(v.w);
        }
        __syncthreads();
        const int n_local = tid >> 2, ch = tid & 3;
        const int j = (kt >> 3) * 512 + nt * 64 + n_local;
        const int d0 = (kt & 7) * 64 + ch * 16;
        us8 o0, o1;
        #pragma unroll
        for (int e = 0; e < 8; ++e) { o0[e] = sT[n_local][ch * 16 + e];
                                      o1[e] = sT[n_local][ch * 16 + 8 + e]; }
        *(us8*)(W1pt + (size_t)j * KD + d0)     = o0;
        *(us8*)(W1pt + (size_t)j * KD + d0 + 8) = o1;
    } else {                                // W2: 131072 elems (512 x 256)
        size_t e = ((size_t)(bid - 8448) * 256 + tid) * 4;
        const int k = (int)(e >> 8), n = (int)(e & 255);
        const int kc = k >> 5, quad = (k >> 3) & 3, pos = k & 7;
        const size_t base = (size_t)kc * 8192 + quad * 8 + pos;
        float4 v = *(const float4*)(W2 + e);
        W2f[base + (size_t)(n + 0) * 32] = f2bf(v.x);
        W2f[base + (size_t)(n + 1) * 32] = f2bf(v.y);
        W2f[base + (size_t)(n + 2) * 32] = f2bf(v.z);
        W2f[base + (size_t)(n + 3) * 32] = f2bf(v.w);
    }
}

// ---------------------------------------------------------------------------
// Dense GEMM1: M=16384, N=2048, K=512; 128m x 256n tile (grid 1024), two
// BK=32 tiles per barrier pair; glds16 staging. Per pair: 12 glds / 64 MFMA
// per wave (vs 8/32 at 128x128). P2[b][nc][node][sg*256+pos] layout kept.
// XCD swizzle: bid&7 = batch.
// ---------------------------------------------------------------------------
__global__ __launch_bounds__(256) void gemm1_dense(
    const ushort_t* __restrict__ h_bf, const ushort_t* __restrict__ W1pt,
    ushort_t* __restrict__ P2)
{
    __shared__ __align__(16) char smem[49152];  // half: A 8KB + B 16KB; x2

    const int tid = threadIdx.x;
    const int w = tid >> 6, lane = tid & 63;
    const int quad = lane >> 4, l16 = lane & 15;
    const int wr = w >> 1, wc = w & 1;          // wave: 64 rows x 128 cols

    const int bid = blockIdx.x;
    const int xcd = bid & 7;                    // == batch
    const int r = bid >> 3;                     // 0..127
    const int m0 = xcd * NNODES + (r & 15) * 128;
    const int n0 = (r >> 4) * 256;              // 8 n-tiles

    const int row0 = tid >> 2, sub = tid & 3;
    const int cg = (sub - (row0 >> 1)) & 3;
    const ushort_t* bA0 = h_bf + (size_t)(m0 + row0) * KD + cg * 8;
    const ushort_t* bA1 = h_bf + (size_t)(m0 + row0 + 64) * KD + cg * 8;
    const ushort_t* bB[4];
    #pragma unroll
    for (int g = 0; g < 4; ++g)
        bB[g] = W1pt + (size_t)(n0 + g * 64 + row0) * KD + cg * 8;

    int pa[4], pb[8];
    #pragma unroll
    for (int i = 0; i < 4; ++i) {
        const int rA = wr * 64 + i * 16 + l16;
        pa[i] = rA * 64 + (((quad + (rA >> 1)) & 3) * 16);
    }
    #pragma unroll
    for (int jf = 0; jf < 8; ++jf) {
        const int rB = wc * 128 + jf * 16 + l16;
        pb[jf] = 8192 + rB * 64 + (((quad + (rB >> 1)) & 3) * 16);
    }

    f32x4 acc[4][8] = {};

    auto stage = [&](int kt, int half) {
        const int oo = kt * 32;
        char* base = smem + half * 24576;
        glds16(bA0 + oo, base + w * 1024);
        glds16(bA1 + oo, base + 4096 + w * 1024);
        #pragma unroll
        for (int g = 0; g < 4; ++g)
            glds16(bB[g] + oo, base + 8192 + g * 4096 + w * 1024);
    };
    auto compute = [&](int half) {
        const char* base = smem + half * 24576;
        bf16x8 bfr[8];
        #pragma unroll
        for (int jf = 0; jf < 8; ++jf)
            bfr[jf] = *(const bf16x8*)(base + pb[jf]);
        #pragma unroll
        for (int i = 0; i < 4; ++i) {
            bf16x8 af = *(const bf16x8*)(base + pa[i]);
            #pragma unroll
            for (int jf = 0; jf < 8; ++jf)
                acc[i][jf] = __builtin_amdgcn_mfma_f32_16x16x32_bf16(
                    af, bfr[jf], acc[i][jf], 0, 0, 0);
        }
    };

    for (int kt = 0; kt < 16; kt += 2) {
        stage(kt, 0);
        stage(kt + 1, 1);
        __syncthreads();
        compute(0);
        compute(1);
        __syncthreads();
    }

    // epilogue: write P2[(b*2+nc)][node][sg*256+pos]
    #pragma unroll
    for (int jf = 0; jf < 8; ++jf) {
        const int j = n0 + wc * 128 + jf * 16 + l16;
        const int sg = j >> 9, nh = j & 511;
        const size_t base = ((size_t)(xcd * 2 + (nh >> 8)) * NNODES) * 1024
                          + (size_t)(sg << 8) + (nh & 255);
        #pragma unroll
        for (int i = 0; i < 4; ++i) {
            f32x4 v = acc[i][jf];
            #pragma unroll
            for (int rr = 0; rr < 4; ++rr) {
                const int node = (m0 + wr * 64 + i * 16 + quad * 4 + rr) & (NNODES - 1);
                P2[base + (size_t)node * 1024] = f2bf(v[rr]);
            }
        }
    }
}

// ---------------------------------------------------------------------------
// FUSED gather + GEMM2 + head, two-phase/one-barrier (r10-proven).
// ---------------------------------------------------------------------------
__global__ __launch_bounds__(512) void fused_tail(
    const ushort_t* __restrict__ P2, const int* __restrict__ idx,
    const float* __restrict__ b1, const ushort_t* __restrict__ W2f,
    const float* __restrict__ b2, const float* __restrict__ W3,
    const float* __restrict__ b3, float* __restrict__ out)
{
    __shared__ __align__(16) char smem[66560];   // A 64KB + red 1KB

    const int tid = threadIdx.x;
    const int w = tid >> 6, lane = tid & 63;
    const int quad = lane >> 4, l16 = lane & 15;

    const int bid = blockIdx.x;
    const int b = bid & 7;
    const int m0 = b * SWAPS + (bid >> 3) * 64;

    // ---------------- Phase 1: gather x1 tile into LDS ----------------
    {
        const int row = tid >> 3;           // 0..63
        const int ws  = tid & 7;
        const int ap  = ws & 3;             // physical 16B chunk
        const int ncs = ws >> 2;            // 0/1 (256-col half)
        const int acg = (ap - (row >> 1)) & 3;
        const int4 iv = *(const int4*)(idx + (size_t)(m0 + row) * 4);
        const ushort_t* Pr = P2 + (size_t)(b * 2 + ncs) * NNODES * 1024;
        const ushort_t* p0 = Pr + (size_t)iv.x * 1024 + 0 * 256;
        const ushort_t* p1 = Pr + (size_t)iv.y * 1024 + 1 * 256;
        const ushort_t* p2 = Pr + (size_t)iv.z * 1024 + 2 * 256;
        const ushort_t* p3 = Pr + (size_t)iv.w * 1024 + 3 * 256;
        #pragma unroll 4
        for (int it = 0; it < 8; ++it) {
            const int kc = ncs * 8 + it;
            const int pos0 = it * 32 + acg * 8;
            us8 v0 = *(const us8*)(p0 + pos0);
            us8 v1 = *(const us8*)(p1 + pos0);
            us8 v2 = *(const us8*)(p2 + pos0);
            us8 v3 = *(const us8*)(p3 + pos0);
            const float* bp = b1 + ncs * 256 + pos0;
            float4 ba = *(const float4*)bp;
            float4 bb = *(const float4*)(bp + 4);
            float s[8] = { ba.x, ba.y, ba.z, ba.w, bb.x, bb.y, bb.z, bb.w };
            #pragma unroll
            for (int e = 0; e < 8; ++e)
                s[e] += bf2f(v0[e]) + bf2f(v1[e]) + bf2f(v2[e]) + bf2f(v3[e]);
            us8 o;
            #pragma unroll
            for (int e = 0; e < 8; ++e) o[e] = f2bf(gelu_fast(s[e]));
            *(us8*)(smem + kc * 4096 + row * 64 + ap * 16) = o;
        }
    }
    __syncthreads();

    // ---------------- Phase 2: barrier-free MFMA ----------------
    const int rg = w >> 2, cg = w & 3;
    int paRow[2];
    #pragma unroll
    for (int i = 0; i < 2; ++i) {
        const int rA = rg * 32 + i * 16 + l16;
        paRow[i] = rA * 64 + (((quad + (rA >> 1)) & 3) * 16);
    }
    const ushort_t* Bbase = W2f + (size_t)(cg * 64 + l16) * 32 + quad * 8;

    f32x4 acc[2][4] = {};

    #pragma unroll 2
    for (int kc = 0; kc < 16; ++kc) {
        bf16x8 af0 = *(const bf16x8*)(smem + kc * 4096 + paRow[0]);
        bf16x8 af1 = *(const bf16x8*)(smem + kc * 4096 + paRow[1]);
        #pragma unroll
        for (int jf = 0; jf < 4; ++jf) {
            bf16x8 bfr = *(const bf16x8*)(Bbase + (size_t)kc * 8192 + jf * 512);
            acc[0][jf] = __builtin_amdgcn_mfma_f32_16x16x32_bf16(af0, bfr, acc[0][jf], 0, 0, 0);
            acc[1][jf] = __builtin_amdgcn_mfma_f32_16x16x32_bf16(af1, bfr, acc[1][jf], 0, 0, 0);
        }
    }

    // ---------------- epilogue: head dot ----------------
    float part[2][4] = {};
    #pragma unroll
    for (int jf = 0; jf < 4; ++jf) {
        const int n = cg * 64 + jf * 16 + l16;
        const float w3 = W3[n];
        const float bb2 = b2[n];
        #pragma unroll
        for (int i = 0; i < 2; ++i) {
            f32x4 v = acc[i][jf];
            #pragma unroll
            for (int rr = 0; rr < 4; ++rr)
                part[i][rr] = fmaf(gelu_fast(v[rr] + bb2), w3, part[i][rr]);
        }
    }
    #pragma unroll
    for (int off = 1; off < 16; off <<= 1)
        #pragma unroll
        for (int i = 0; i < 2; ++i)
            #pragma unroll
            for (int rr = 0; rr < 4; ++rr)
                part[i][rr] += __shfl_xor(part[i][rr], off);

    float* red = (float*)(smem + 65536);    // red[4][64]
    if (l16 == 0) {
        #pragma unroll
        for (int i = 0; i < 2; ++i)
            #pragma unroll
            for (int rr = 0; rr < 4; ++rr)
                red[cg * 64 + rg * 32 + i * 16 + quad * 4 + rr] = part[i][rr];
    }
    __syncthreads();
    if (tid < 64) {
        const float v = red[tid] + red[64 + tid] + red[128 + tid] + red[192 + tid];
        out[m0 + tid] = softplus_f(v + b3[0]);
    }
}

// ---------------------------------------------------------------------------
// Workspace (peak 82.25 MB):
//   P2 @ 0 : 64 MB;  h_bf @ 64M : 16 MB;  W1pt @ 80M : 2 MB;  W2f @ 82M : 256KB
// ---------------------------------------------------------------------------
extern "C" void kernel_launch(void* const* d_in, const int* in_sizes, int n_in,
                              void* d_out, int out_size, void* d_ws, size_t ws_size,
                              hipStream_t stream) {
    const float* h   = (const float*)d_in[0];
    const int*   idx = (const int*)d_in[1];
    const float* W1  = (const float*)d_in[2];
    const float* b1  = (const float*)d_in[3];
    const float* W2  = (const float*)d_in[4];
    const float* b2  = (const float*)d_in[5];
    const float* W3  = (const float*)d_in[6];
    const float* b3  = (const float*)d_in[7];
    float* out = (float*)d_out;

    char* ws = (char*)d_ws;
    ushort_t* P2    = (ushort_t*)ws;
    ushort_t* h_bf  = (ushort_t*)(ws + (64u << 20));
    ushort_t* W1pt  = (ushort_t*)(ws + (80u << 20));
    ushort_t* W2f   = (ushort_t*)(ws + (82u << 20));

    convert_kernel<<<8576, 256, 0, stream>>>(h, W1, W2, h_bf, W1pt, W2f);
    gemm1_dense<<<1024, 256, 0, stream>>>(h_bf, W1pt, P2);
    fused_tail<<<512, 512, 0, stream>>>(P2, idx, b1, W2f, b2, W3, b3, out);
}

// Round 13
// 170.548 us; speedup vs baseline: 1.2059x; 1.2059x over previous
//
#include <hip/hip_runtime.h>
#include <math.h>

// Problem constants: B=8, N=2048, D=512, S=4096
#define BATCH 8
#define NNODES 2048
#define DDIM 512
#define SWAPS 4096
#define M_TOTAL (BATCH * SWAPS)   // 32768
#define KD DDIM                   // 512 (dense GEMM K)
#define K2 DDIM                   // 512
#define N2 (DDIM / 2)             // 256

typedef __attribute__((ext_vector_type(8))) __bf16 bf16x8;   // MFMA A/B frag
typedef __attribute__((ext_vector_type(4))) float f32x4;      // MFMA C/D frag
typedef __attribute__((ext_vector_type(8))) unsigned short us8;
typedef unsigned short ushort_t;

// tanh-approx GELU (max |err| vs exact erf-GELU ~5e-4)
__device__ __forceinline__ float gelu_fast(float x) {
    const float u = 0.7978845608028654f * x * fmaf(0.044715f * x, x, 1.0f);
    const float e = __expf(-2.0f * fabsf(u));
    float t = (1.0f - e) / (1.0f + e);
    t = copysignf(t, u);
    return 0.5f * x * (1.0f + t);
}
__device__ __forceinline__ float softplus_f(float x) {
    return fmaxf(x, 0.0f) + log1pf(expf(-fabsf(x)));
}
__device__ __forceinline__ unsigned short f2bf(float f) {
    unsigned int u = __builtin_bit_cast(unsigned int, f);
    u += 0x7FFFu + ((u >> 16) & 1u);
    return (unsigned short)(u >> 16);
}
__device__ __forceinline__ float bf2f(unsigned short s) {
    return __builtin_bit_cast(float, (unsigned int)s << 16);
}
__device__ __forceinline__ void glds16(const void* g, void* l) {
    __builtin_amdgcn_global_load_lds(
        (const __attribute__((address_space(1))) void*)g,
        (__attribute__((address_space(3))) void*)l, 16, 0, 0);
}

// ---------------------------------------------------------------------------
// convert: h -> h_bf via us8 16B stores (4096 blocks);
// W1 -> W1pt[j][d] via LDS transpose -> CONTIGUOUS 16B global stores
// (r11-verified; the old scattered 2B-store path cost ~50 us in write sectors);
// W2 -> W2f fragment-major [kc*8192 + n*32 + quad*8 + pos].
// ---------------------------------------------------------------------------
__global__ __launch_bounds__(256) void convert_kernel(
    const float* __restrict__ h, const float* __restrict__ W1,
    const float* __restrict__ W2, ushort_t* __restrict__ h_bf,
    ushort_t* __restrict__ W1pt, ushort_t* __restrict__ W2f)
{
    const int bid = blockIdx.x;
    const int tid = threadIdx.x;
    if (bid < 4096) {                       // h: 8M elems, 8/thread
        const size_t i = ((size_t)bid * 256 + tid) * 8;
        float4 v0 = *(const float4*)(h + i);
        float4 v1 = *(const float4*)(h + i + 4);
        us8 o;
        o[0] = f2bf(v0.x); o[1] = f2bf(v0.y); o[2] = f2bf(v0.z); o[3] = f2bf(v0.w);
        o[4] = f2bf(v1.x); o[5] = f2bf(v1.y); o[6] = f2bf(v1.z); o[7] = f2bf(v1.w);
        *(us8*)(h_bf + i) = o;
    } else if (bid < 4096 + 256) {          // W1 transpose: 64k x 64n tiles
        __shared__ ushort_t sT[64][72];     // [n_local][k_local+pad]
        const int tb = bid - 4096;
        const int kt = tb >> 3, nt = tb & 7;     // 32 k-tiles, 8 n-tiles
        const int kl = tid >> 4;                 // 0..15 (per pass)
        const int n4 = (tid & 15) * 4;
        #pragma unroll
        for (int p = 0; p < 4; ++p) {
            const int k_local = p * 16 + kl;
            float4 v = *(const float4*)(W1 + (size_t)(kt * 64 + k_local) * 512
                                        + nt * 64 + n4);
            sT[n4 + 0][k_local] = f2bf(v.x);
            sT[n4 + 1][k_local] = f2bf(v.y);
            sT[n4 + 2][k_local] = f2bf(v.z);
            sT[n4 + 3][k_local] = f2bf(v.w);
        }
        __syncthreads();
        const int n_local = tid >> 2, ch = tid & 3;
        const int j = (kt >> 3) * 512 + nt * 64 + n_local;
        const int d0 = (kt & 7) * 64 + ch * 16;
        us8 o0, o1;
        #pragma unroll
        for (int e = 0; e < 8; ++e) { o0[e] = sT[n_local][ch * 16 + e];
                                      o1[e] = sT[n_local][ch * 16 + 8 + e]; }
        *(us8*)(W1pt + (size_t)j * KD + d0)     = o0;
        *(us8*)(W1pt + (size_t)j * KD + d0 + 8) = o1;
    } else {                                // W2: 131072 elems (512 x 256)
        size_t e = ((size_t)(bid - 4352) * 256 + tid) * 4;
        const int k = (int)(e >> 8), n = (int)(e & 255);
        const int kc = k >> 5, quad = (k >> 3) & 3, pos = k & 7;
        const size_t base = (size_t)kc * 8192 + quad * 8 + pos;
        float4 v = *(const float4*)(W2 + e);
        W2f[base + (size_t)(n + 0) * 32] = f2bf(v.x);
        W2f[base + (size_t)(n + 1) * 32] = f2bf(v.y);
        W2f[base + (size_t)(n + 2) * 32] = f2bf(v.z);
        W2f[base + (size_t)(n + 3) * 32] = f2bf(v.w);
    }
}

// ---------------------------------------------------------------------------
// Dense GEMM1 (r10-proven, 51 us): M=16384, N=2048, K=512; 128x128 tile; two
// BK=32 tiles per barrier pair; glds16 staging of bf16 h_bf + W1pt.
// P2[b][nc][node][sg*256+pos]: per-(b,nc) region = 4MB = one XCD L2.
// XCD swizzle: bid&7 = batch.
// ---------------------------------------------------------------------------
__global__ __launch_bounds__(256) void gemm1_dense(
    const ushort_t* __restrict__ h_bf, const ushort_t* __restrict__ W1pt,
    ushort_t* __restrict__ P2)
{
    __shared__ __align__(16) char smem[32768];

    const int tid = threadIdx.x;
    const int w = tid >> 6, lane = tid & 63;
    const int quad = lane >> 4, l16 = lane & 15;
    const int wr = w >> 1, wc = w & 1;

    const int bid = blockIdx.x;
    const int xcd = bid & 7;            // == batch
    const int r = bid >> 3;
    const int m0 = xcd * NNODES + (r & 15) * 128;
    const int n0 = (r >> 4) * 128;

    const int row0 = tid >> 2, sub = tid & 3;
    const int cg = (sub - (row0 >> 1)) & 3;
    const ushort_t* bA0 = h_bf + (size_t)(m0 + row0) * KD + cg * 8;
    const ushort_t* bA1 = h_bf + (size_t)(m0 + row0 + 64) * KD + cg * 8;
    const ushort_t* bB0 = W1pt + (size_t)(n0 + row0) * KD + cg * 8;
    const ushort_t* bB1 = W1pt + (size_t)(n0 + row0 + 64) * KD + cg * 8;

    int pa[4], pb[4];
    #pragma unroll
    for (int i = 0; i < 4; ++i) {
        const int rA = wr * 64 + i * 16 + l16;
        const int rB = wc * 64 + i * 16 + l16;
        pa[i] = rA * 64 + (((quad + (rA >> 1)) & 3) * 16);
        pb[i] = 8192 + rB * 64 + (((quad + (rB >> 1)) & 3) * 16);
    }

    f32x4 acc[4][4] = {};

    auto stage = [&](int kt, int half) {
        const int oo = kt * 32;
        char* base = smem + half * 16384;
        glds16(bA0 + oo, base + w * 1024);
        glds16(bA1 + oo, base + 4096 + w * 1024);
        glds16(bB0 + oo, base + 8192 + w * 1024);
        glds16(bB1 + oo, base + 12288 + w * 1024);
    };
    auto compute = [&](int half) {
        const char* base = smem + half * 16384;
        bf16x8 af[4], bfr[4];
        #pragma unroll
        for (int i = 0; i < 4; ++i) {
            af[i]  = *(const bf16x8*)(base + pa[i]);
            bfr[i] = *(const bf16x8*)(base + pb[i]);
        }
        #pragma unroll
        for (int i = 0; i < 4; ++i)
            #pragma unroll
            for (int jj = 0; jj < 4; ++jj)
                acc[i][jj] = __builtin_amdgcn_mfma_f32_16x16x32_bf16(
                    af[i], bfr[jj], acc[i][jj], 0, 0, 0);
    };

    for (int kt = 0; kt < 16; kt += 2) {
        stage(kt, 0);
        stage(kt + 1, 1);
        __syncthreads();
        compute(0);
        compute(1);
        __syncthreads();
    }

    // epilogue: write P2[(b*2+nc)][node][sg*256+pos]
    #pragma unroll
    for (int jj = 0; jj < 4; ++jj) {
        const int j = n0 + wc * 64 + jj * 16 + l16;
        const int sg = j >> 9, nh = j & 511;
        const size_t base = ((size_t)(xcd * 2 + (nh >> 8)) * NNODES) * 1024
                          + (size_t)(sg << 8) + (nh & 255);
        #pragma unroll
        for (int i = 0; i < 4; ++i) {
            f32x4 v = acc[i][jj];
            #pragma unroll
            for (int rr = 0; rr < 4; ++rr) {
                const int node = (m0 + wr * 64 + i * 16 + quad * 4 + rr) & (NNODES - 1);
                P2[base + (size_t)node * 1024] = f2bf(v[rr]);
            }
        }
    }
}

// ---------------------------------------------------------------------------
// FUSED gather + GEMM2 + head, two-phase/one-barrier (r10-proven).
// ---------------------------------------------------------------------------
__global__ __launch_bounds__(512) void fused_tail(
    const ushort_t* __restrict__ P2, const int* __restrict__ idx,
    const float* __restrict__ b1, const ushort_t* __restrict__ W2f,
    const float* __restrict__ b2, const float* __restrict__ W3,
    const float* __restrict__ b3, float* __restrict__ out)
{
    __shared__ __align__(16) char smem[66560];   // A 64KB + red 1KB

    const int tid = threadIdx.x;
    const int w = tid >> 6, lane = tid & 63;
    const int quad = lane >> 4, l16 = lane & 15;

    const int bid = blockIdx.x;
    const int b = bid & 7;
    const int m0 = b * SWAPS + (bid >> 3) * 64;

    // ---------------- Phase 1: gather x1 tile into LDS ----------------
    {
        const int row = tid >> 3;           // 0..63
        const int ws  = tid & 7;
        const int ap  = ws & 3;             // physical 16B chunk
        const int ncs = ws >> 2;            // 0/1 (256-col half)
        const int acg = (ap - (row >> 1)) & 3;
        const int4 iv = *(const int4*)(idx + (size_t)(m0 + row) * 4);
        const ushort_t* Pr = P2 + (size_t)(b * 2 + ncs) * NNODES * 1024;
        const ushort_t* p0 = Pr + (size_t)iv.x * 1024 + 0 * 256;
        const ushort_t* p1 = Pr + (size_t)iv.y * 1024 + 1 * 256;
        const ushort_t* p2 = Pr + (size_t)iv.z * 1024 + 2 * 256;
        const ushort_t* p3 = Pr + (size_t)iv.w * 1024 + 3 * 256;
        #pragma unroll 4
        for (int it = 0; it < 8; ++it) {
            const int kc = ncs * 8 + it;
            const int pos0 = it * 32 + acg * 8;
            us8 v0 = *(const us8*)(p0 + pos0);
            us8 v1 = *(const us8*)(p1 + pos0);
            us8 v2 = *(const us8*)(p2 + pos0);
            us8 v3 = *(const us8*)(p3 + pos0);
            const float* bp = b1 + ncs * 256 + pos0;
            float4 ba = *(const float4*)bp;
            float4 bb = *(const float4*)(bp + 4);
            float s[8] = { ba.x, ba.y, ba.z, ba.w, bb.x, bb.y, bb.z, bb.w };
            #pragma unroll
            for (int e = 0; e < 8; ++e)
                s[e] += bf2f(v0[e]) + bf2f(v1[e]) + bf2f(v2[e]) + bf2f(v3[e]);
            us8 o;
            #pragma unroll
            for (int e = 0; e < 8; ++e) o[e] = f2bf(gelu_fast(s[e]));
            *(us8*)(smem + kc * 4096 + row * 64 + ap * 16) = o;
        }
    }
    __syncthreads();

    // ---------------- Phase 2: barrier-free MFMA ----------------
    const int rg = w >> 2, cg = w & 3;
    int paRow[2];
    #pragma unroll
    for (int i = 0; i < 2; ++i) {
        const int rA = rg * 32 + i * 16 + l16;
        paRow[i] = rA * 64 + (((quad + (rA >> 1)) & 3) * 16);
    }
    const ushort_t* Bbase = W2f + (size_t)(cg * 64 + l16) * 32 + quad * 8;

    f32x4 acc[2][4] = {};

    #pragma unroll 2
    for (int kc = 0; kc < 16; ++kc) {
        bf16x8 af0 = *(const bf16x8*)(smem + kc * 4096 + paRow[0]);
        bf16x8 af1 = *(const bf16x8*)(smem + kc * 4096 + paRow[1]);
        #pragma unroll
        for (int jf = 0; jf < 4; ++jf) {
            bf16x8 bfr = *(const bf16x8*)(Bbase + (size_t)kc * 8192 + jf * 512);
            acc[0][jf] = __builtin_amdgcn_mfma_f32_16x16x32_bf16(af0, bfr, acc[0][jf], 0, 0, 0);
            acc[1][jf] = __builtin_amdgcn_mfma_f32_16x16x32_bf16(af1, bfr, acc[1][jf], 0, 0, 0);
        }
    }

    // ---------------- epilogue: head dot ----------------
    float part[2][4] = {};
    #pragma unroll
    for (int jf = 0; jf < 4; ++jf) {
        const int n = cg * 64 + jf * 16 + l16;
        const float w3 = W3[n];
        const float bb2 = b2[n];
        #pragma unroll
        for (int i = 0; i < 2; ++i) {
            f32x4 v = acc[i][jf];
            #pragma unroll
            for (int rr = 0; rr < 4; ++rr)
                part[i][rr] = fmaf(gelu_fast(v[rr] + bb2), w3, part[i][rr]);
        }
    }
    #pragma unroll
    for (int off = 1; off < 16; off <<= 1)
        #pragma unroll
        for (int i = 0; i < 2; ++i)
            #pragma unroll
            for (int rr = 0; rr < 4; ++rr)
                part[i][rr] += __shfl_xor(part[i][rr], off);

    float* red = (float*)(smem + 65536);    // red[4][64]
    if (l16 == 0) {
        #pragma unroll
        for (int i = 0; i < 2; ++i)
            #pragma unroll
            for (int rr = 0; rr < 4; ++rr)
                red[cg * 64 + rg * 32 + i * 16 + quad * 4 + rr] = part[i][rr];
    }
    __syncthreads();
    if (tid < 64) {
        const float v = red[tid] + red[64 + tid] + red[128 + tid] + red[192 + tid];
        out[m0 + tid] = softplus_f(v + b3[0]);
    }
}

// ---------------------------------------------------------------------------
// Workspace (peak 82.25 MB):
//   P2 @ 0 : 64 MB;  h_bf @ 64M : 16 MB;  W1pt @ 80M : 2 MB;  W2f @ 82M : 256KB
// ---------------------------------------------------------------------------
extern "C" void kernel_launch(void* const* d_in, const int* in_sizes, int n_in,
                              void* d_out, int out_size, void* d_ws, size_t ws_size,
                              hipStream_t stream) {
    const float* h   = (const float*)d_in[0];
    const int*   idx = (const int*)d_in[1];
    const float* W1  = (const float*)d_in[2];
    const float* b1  = (const float*)d_in[3];
    const float* W2  = (const float*)d_in[4];
    const float* b2  = (const float*)d_in[5];
    const float* W3  = (const float*)d_in[6];
    const float* b3  = (const float*)d_in[7];
    float* out = (float*)d_out;

    char* ws = (char*)d_ws;
    ushort_t* P2    = (ushort_t*)ws;
    ushort_t* h_bf  = (ushort_t*)(ws + (64u << 20));
    ushort_t* W1pt  = (ushort_t*)(ws + (80u << 20));
    ushort_t* W2f   = (ushort_t*)(ws + (82u << 20));

    convert_kernel<<<4480, 256, 0, stream>>>(h, W1, W2, h_bf, W1pt, W2f);
    gemm1_dense<<<2048, 256, 0, stream>>>(h_bf, W1pt, P2);
    fused_tail<<<512, 512, 0, stream>>>(P2, idx, b1, W2f, b2, W3, b3, out);
}